// Round 2
// baseline (427.085 us; speedup 1.0000x reference)
//
#include <hip/hip_runtime.h>

#define NVEC 65536   // B*H*W = 64*32*32
#define KC   1024
#define DD   64

// d_out layout (f32): [0]=loss, [1..4194305)=z_q (B,D,H,W), [4194305]=perplexity, [4194306..)=idx
#define OUT_ZQ   1
#define OUT_PPL  4194305
#define OUT_IDX  4194306
// zt scratch lives at out+4 (16B aligned), spans [4, 4+NVEC*64) — fully
// overwritten later by epilogue/final writes of zq/ppl/idx.
#define OUT_ZT   4

// ws layout (bytes)
#define WS_KEYS  0                        // u64[NVEC]   = 524288
#define WS_HIST  524288                   // int[KC]     = 4096
#define WS_SUMSQ 528384                   // double      = 8
#define WS_SE    528392                   // float[KC]   = 4096

// ---------------------------------------------------------------------------
// prep_z: transpose z[b][c][hw] -> zt[n][c] (contiguous rows) and compute
// sz[n] = np.sum(zf**2, axis=1) with numpy's exact pairwise order (n=64):
// 8 accumulators striding by 8, combined ((r0+r1)+(r2+r3))+((r4+r5)+(r6+r7)).
__global__ __launch_bounds__(256) void prep_z(const float* __restrict__ z,
                                              float* __restrict__ zt,
                                              float* __restrict__ sz) {
    const int b   = blockIdx.x >> 2;
    const int hw  = (blockIdx.x & 3) * 256 + threadIdx.x;
    const int n   = b * 1024 + hw;
    const float* zp = z + (size_t)b * 65536 + hw;   // stride 1024 over c
    float4* zt4 = (float4*)(zt + (size_t)n * 64);

    float r[8];
    float4 pack;
    #pragma unroll
    for (int c = 0; c < 64; ++c) {
        float v = zp[(size_t)c * 1024];
        float s = __fmul_rn(v, v);
        if (c < 8) r[c] = s;
        else       r[c & 7] = __fadd_rn(r[c & 7], s);
        ((float*)&pack)[c & 3] = v;
        if ((c & 3) == 3) zt4[c >> 2] = pack;
    }
    float res = __fadd_rn(__fadd_rn(__fadd_rn(r[0], r[1]), __fadd_rn(r[2], r[3])),
                          __fadd_rn(__fadd_rn(r[4], r[5]), __fadd_rn(r[6], r[7])));
    sz[n] = res;
}

// prep_emb: se[k] = np.sum(emb**2, axis=1), same pairwise emulation, f32.
__global__ __launch_bounds__(256) void prep_emb(const float* __restrict__ emb,
                                                float* __restrict__ se) {
    const int k = blockIdx.x * 256 + threadIdx.x;
    const float* er = emb + (size_t)k * 64;
    float r[8];
    #pragma unroll
    for (int c = 0; c < 64; ++c) {
        float v = er[c];
        float s = __fmul_rn(v, v);
        if (c < 8) r[c] = s;
        else       r[c & 7] = __fadd_rn(r[c & 7], s);
    }
    se[k] = __fadd_rn(__fadd_rn(__fadd_rn(r[0], r[1]), __fadd_rn(r[2], r[3])),
                      __fadd_rn(__fadd_rn(r[4], r[5]), __fadd_rn(r[6], r[7])));
}

// ---------------------------------------------------------------------------
// dist: lane <-> one code k (emb row in 64 VGPRs); loop over 256 n per block.
// M[n,k] = sequential __fmaf_rn chain over c=0..63 (BLAS sgemm order).
// d = fl32( fl32(sz[n] + se[k]) - 2*M ), argmin, first-index tie-break.
__global__ __launch_bounds__(256, 4) void dist_kernel(const float* __restrict__ zt,
                                                      const float* __restrict__ sz,
                                                      const float* __restrict__ emb,
                                                      const float* __restrict__ se,
                                                      unsigned long long* __restrict__ keys) {
    const int lane = threadIdx.x & 63;
    const int w    = threadIdx.x >> 6;
    const int k    = blockIdx.y * 256 + w * 64 + lane;

    float e[64];
    const float4* ep = (const float4*)(emb + (size_t)k * 64);
    #pragma unroll
    for (int q = 0; q < 16; ++q) {
        float4 t = ep[q];
        e[q * 4 + 0] = t.x; e[q * 4 + 1] = t.y;
        e[q * 4 + 2] = t.z; e[q * 4 + 3] = t.w;
    }
    const float sek = se[k];
    const int nbase = blockIdx.x * 256;

    for (int nn = 0; nn < 256; nn += 4) {
        const int n0 = nbase + nn;
        const float4* z0 = (const float4*)(zt + (size_t)(n0 + 0) * 64);
        const float4* z1 = (const float4*)(zt + (size_t)(n0 + 1) * 64);
        const float4* z2 = (const float4*)(zt + (size_t)(n0 + 2) * 64);
        const float4* z3 = (const float4*)(zt + (size_t)(n0 + 3) * 64);
        float a0 = 0.f, a1 = 0.f, a2 = 0.f, a3 = 0.f;
        #pragma unroll
        for (int q = 0; q < 16; ++q) {
            float4 t0 = z0[q], t1 = z1[q], t2 = z2[q], t3 = z3[q];
            a0 = __fmaf_rn(t0.x, e[q*4+0], a0);
            a0 = __fmaf_rn(t0.y, e[q*4+1], a0);
            a0 = __fmaf_rn(t0.z, e[q*4+2], a0);
            a0 = __fmaf_rn(t0.w, e[q*4+3], a0);
            a1 = __fmaf_rn(t1.x, e[q*4+0], a1);
            a1 = __fmaf_rn(t1.y, e[q*4+1], a1);
            a1 = __fmaf_rn(t1.z, e[q*4+2], a1);
            a1 = __fmaf_rn(t1.w, e[q*4+3], a1);
            a2 = __fmaf_rn(t2.x, e[q*4+0], a2);
            a2 = __fmaf_rn(t2.y, e[q*4+1], a2);
            a2 = __fmaf_rn(t2.z, e[q*4+2], a2);
            a2 = __fmaf_rn(t2.w, e[q*4+3], a2);
            a3 = __fmaf_rn(t3.x, e[q*4+0], a3);
            a3 = __fmaf_rn(t3.y, e[q*4+1], a3);
            a3 = __fmaf_rn(t3.z, e[q*4+2], a3);
            a3 = __fmaf_rn(t3.w, e[q*4+3], a3);
        }
        float accs[4] = {a0, a1, a2, a3};
        #pragma unroll
        for (int j = 0; j < 4; ++j) {
            float d = __fsub_rn(__fadd_rn(sz[n0 + j], sek),
                                __fmul_rn(2.0f, accs[j]));
            unsigned m = __float_as_uint(d);
            m ^= ((int)m < 0) ? 0xFFFFFFFFu : 0x80000000u;
            unsigned wm = m;
            #pragma unroll
            for (int off = 32; off; off >>= 1) {
                unsigned o = (unsigned)__shfl_xor((int)wm, off, 64);
                wm = (o < wm) ? o : wm;
            }
            if (m == wm) {
                unsigned long long key =
                    ((unsigned long long)m << 32) | (unsigned)k;
                atomicMin(&keys[n0 + j], key);
            }
        }
    }
}

// ---------------------------------------------------------------------------
__global__ __launch_bounds__(256) void epilogue_kernel(const float* __restrict__ z,
                                                       const float* __restrict__ emb,
                                                       const unsigned long long* __restrict__ keys,
                                                       float* __restrict__ out,
                                                       int* __restrict__ hist,
                                                       double* __restrict__ sumsq) {
    __shared__ double red[256];
    const int tid = threadIdx.x;
    const int n   = blockIdx.x * 256 + tid;
    const int b   = n >> 10;
    const int hw  = n & 1023;
    const int idx = (int)(keys[n] & 0xFFFFFFFFULL);

    out[OUT_IDX + n] = (float)idx;
    atomicAdd(&hist[idx], 1);

    const float* zp = z   + (size_t)b * 65536 + hw;
    float*       op = out + OUT_ZQ + (size_t)b * 65536 + hw;
    const float* er = emb + (size_t)idx * DD;
    double s = 0.0;
    #pragma unroll
    for (int c = 0; c < DD; ++c) {
        float zv   = zp[(size_t)c * 1024];
        float ev   = er[c];
        float diff = ev - zv;                  // z_q - z
        op[(size_t)c * 1024] = zv + diff;      // straight-through: z + sg(z_q - z)
        s = fma((double)diff, (double)diff, s);
    }
    red[tid] = s;
    __syncthreads();
    for (int off = 128; off > 0; off >>= 1) {
        if (tid < off) red[tid] += red[tid + off];
        __syncthreads();
    }
    if (tid == 0) atomicAdd(sumsq, red[0]);
}

__global__ __launch_bounds__(256) void final_kernel(const int* __restrict__ hist,
                                                    const double* __restrict__ sumsq,
                                                    float* __restrict__ out) {
    __shared__ double red[256];
    const int tid = threadIdx.x;
    double s = 0.0;
    #pragma unroll
    for (int j = 0; j < 4; ++j) {
        int   kk = j * 256 + tid;
        float em = (float)hist[kk] * (1.0f / 65536.0f);
        float t  = em * logf(em + 1e-10f);
        s += (double)t;
    }
    red[tid] = s;
    __syncthreads();
    for (int off = 128; off > 0; off >>= 1) {
        if (tid < off) red[tid] += red[tid + off];
        __syncthreads();
    }
    if (tid == 0) {
        out[OUT_PPL] = expf(-(float)red[0]);
        out[0]       = 1.25f * (float)(sumsq[0] / 4194304.0);
    }
}

extern "C" void kernel_launch(void* const* d_in, const int* in_sizes, int n_in,
                              void* d_out, int out_size, void* d_ws, size_t ws_size,
                              hipStream_t stream) {
    const float* z   = (const float*)d_in[0];
    const float* emb = (const float*)d_in[1];
    float* out = (float*)d_out;
    char*  ws  = (char*)d_ws;

    unsigned long long* keys  = (unsigned long long*)(ws + WS_KEYS);
    int*                hist  = (int*)(ws + WS_HIST);
    double*             sumsq = (double*)(ws + WS_SUMSQ);
    float*              se    = (float*)(ws + WS_SE);
    float*              sz    = out + OUT_IDX;      // reuse idx region? NO — use ws below
    // sz goes in ws right after se:
    sz = (float*)(ws + WS_SE + KC * 4);
    float* zt = out + OUT_ZT;   // staged transpose, overwritten later by zq/idx writes

    hipMemsetAsync(keys, 0xFF, (size_t)NVEC * 8, stream);
    hipMemsetAsync(hist, 0, (size_t)KC * 4 + 8, stream);  // hist + sumsq contiguous

    prep_z<<<256, 256, 0, stream>>>(z, zt, sz);
    prep_emb<<<KC / 256, 256, 0, stream>>>(emb, se);
    dist_kernel<<<dim3(NVEC / 256, 4), 256, 0, stream>>>(zt, sz, emb, se, keys);
    epilogue_kernel<<<NVEC / 256, 256, 0, stream>>>(z, emb, keys, out, hist, sumsq);
    final_kernel<<<1, 256, 0, stream>>>(hist, sumsq, out);
}